// Round 2
// baseline (12015.480 us; speedup 1.0000x reference)
//
#include <hip/hip_runtime.h>

typedef __attribute__((ext_vector_type(8))) short short8;
typedef __attribute__((ext_vector_type(4))) float f32x4;

#define MFMA(a,b,c) __builtin_amdgcn_mfma_f32_16x16x32_bf16((a),(b),(c),0,0,0)

#define B_  16
#define S_  512
#define DM_ 768
#define H_  640
#define G4_ 2560
#define DA_ 1280
#define NH_ 10
#define HD_ 128

static __device__ __forceinline__ unsigned short f2bf(float v) {
  unsigned u = __builtin_bit_cast(unsigned, v);
  u = (u + 0x7fffu + ((u >> 16) & 1u)) >> 16;
  return (unsigned short)u;
}
static __device__ __forceinline__ float bf2f(unsigned short u) {
  return __builtin_bit_cast(float, (unsigned)u << 16);
}
static __device__ __forceinline__ float sigm(float x) { return 1.0f / (1.0f + __expf(-x)); }
static __device__ __forceinline__ float tanh_c(float x) {
  x = fminf(fmaxf(x, -15.0f), 15.0f);
  float e = __expf(2.0f * x);
  return (e - 1.0f) / (e + 1.0f);
}

// ---------------------------------------------------------------- cast f32->bf16
__global__ __launch_bounds__(256)
void cast_f32_bf16(const float* __restrict__ src, unsigned short* __restrict__ dst, int n4) {
  int i = blockIdx.x * 256 + threadIdx.x;
  if (i >= n4) return;
  float4 v = reinterpret_cast<const float4*>(src)[i];
  ushort4 o;
  o.x = f2bf(v.x); o.y = f2bf(v.y); o.z = f2bf(v.z); o.w = f2bf(v.w);
  reinterpret_cast<ushort4*>(dst)[i] = o;
}

// ---------------------------------------------------------------- GEMM  C = A @ W^T + bias
// A: (M,K) bf16 row-major; W: (N,K) bf16 row-major; M,N%128==0, K%32==0.
// OUT_MODE 0: f32 C[M][N]; 1: bf16 C[M][N]; 2: bf16 transposed-per-head V layout
__device__ __forceinline__ void gload_lds16(void* lds, const void* g) {
  __builtin_amdgcn_global_load_lds(
      (const __attribute__((address_space(1))) unsigned int*)g,
      (__attribute__((address_space(3))) unsigned int*)lds, 16, 0, 0);
}

template<int OUT_MODE>
__global__ __launch_bounds__(256)
void gemm_abt(const unsigned short* __restrict__ A, const unsigned short* __restrict__ W,
              const float* __restrict__ bias, void* __restrict__ Cout,
              int M, int N, int K) {
  __shared__ unsigned short lA[128 * 32];
  __shared__ unsigned short lB[128 * 32];
  const int tid = threadIdx.x;
  const int lane = tid & 63, wid = tid >> 6;
  const int nbn = N >> 7;
  const int mi = blockIdx.x / nbn, ni = blockIdx.x % nbn;
  const int l15 = lane & 15, lq = lane >> 4;

  f32x4 acc[4][4] = {};

  for (int k0 = 0; k0 < K; k0 += 32) {
#pragma unroll
    for (int part = 0; part < 2; ++part) {
      int linear = part * 256 + tid;
      int r = linear >> 2, cc = linear & 3;
      const unsigned short* ga = A + (size_t)(mi * 128 + r) * K + k0 + cc * 8;
      const unsigned short* gb = W + (size_t)(ni * 128 + r) * K + k0 + cc * 8;
      gload_lds16(&lA[(part * 256 + wid * 64) * 8], ga);
      gload_lds16(&lB[(part * 256 + wid * 64) * 8], gb);
    }
    __syncthreads();
    const int wm = (wid >> 1) * 64, wn = (wid & 1) * 64;
    short8 af[4], bfr[4];
#pragma unroll
    for (int m = 0; m < 4; ++m)
      af[m] = *(const short8*)&lA[(wm + m * 16 + l15) * 32 + lq * 8];
#pragma unroll
    for (int n = 0; n < 4; ++n)
      bfr[n] = *(const short8*)&lB[(wn + n * 16 + l15) * 32 + lq * 8];
#pragma unroll
    for (int m = 0; m < 4; ++m)
#pragma unroll
      for (int n = 0; n < 4; ++n)
        acc[m][n] = MFMA(af[m], bfr[n], acc[m][n]);
    __syncthreads();
  }

  const int wm = (wid >> 1) * 64, wn = (wid & 1) * 64;
#pragma unroll
  for (int n = 0; n < 4; ++n) {
    int col = ni * 128 + wn + n * 16 + l15;
    float bv = bias[col];
#pragma unroll
    for (int m = 0; m < 4; ++m) {
#pragma unroll
      for (int r = 0; r < 4; ++r) {
        int row = mi * 128 + wm + m * 16 + lq * 4 + r;
        float v = acc[m][n][r] + bv;
        if (OUT_MODE == 0) {
          ((float*)Cout)[(size_t)row * N + col] = v;
        } else if (OUT_MODE == 1) {
          ((unsigned short*)Cout)[(size_t)row * N + col] = f2bf(v);
        } else {
          int bb = row >> 9, s = row & 511, hh = col >> 7, d = col & 127;
          ((unsigned short*)Cout)[(((size_t)(bb * NH_ + hh) * HD_ + d) << 9) + s] = f2bf(v);
        }
      }
    }
  }
}

// ---------------------------------------------------------------- persistent BiLSTM layer
// grid = 64 WGs (32 per direction), 320 threads (5 waves). Each WG owns 20 hidden
// units => 80 rows of Whh cached in static LDS (bf16). h exchanged via global +
// per-direction flag barrier (device-scope fences for cross-XCD visibility).
template<bool XPF32>
__global__ __launch_bounds__(320)
void bilstm_layer(const void* __restrict__ xp_,           // [2][B][S][2560] f32 or bf16
                  const unsigned short* __restrict__ whh_g,// [2][2560][640] bf16
                  const int* __restrict__ lengths,         // [B]
                  unsigned short* __restrict__ h_ex,       // [2][2][B][640] bf16
                  int* __restrict__ flags, int flag_base,
                  unsigned short* __restrict__ out_bf)     // [B*S][1280] bf16
{
  __shared__ unsigned short whh[80 * 648];
  __shared__ unsigned short hbuf[16 * 648];
  __shared__ float pre[16 * 80];
  __shared__ float cst[320];
  __shared__ float hst[320];
  __shared__ int len_s[16];

  const int tid = threadIdx.x;
  const int lane = tid & 63, wid = tid >> 6;
  const int wg = blockIdx.x;
  const int dir = wg >> 5, slice = wg & 31;
  const int J0 = slice * 20;
  const int l15 = lane & 15, lq = lane >> 4;

  for (int c = tid; c < 80 * 160; c += 320) {
    int r = c / 160, c4 = c % 160;
    int grow = (r / 20) * H_ + J0 + (r % 20);
    *(ushort4*)&whh[r * 648 + c4 * 4] =
        *(const ushort4*)&whh_g[((size_t)dir * G4_ + grow) * H_ + c4 * 4];
  }
  if (tid < 16) len_s[tid] = lengths[tid];
  cst[tid] = 0.f; hst[tid] = 0.f;
  __syncthreads();

  for (int s = 0; s < S_; ++s) {
    const int t = dir ? (S_ - 1 - s) : s;
    {
      const unsigned short* src = h_ex + ((size_t)(dir * 2 + (s & 1)) * B_) * H_;
      for (int c = tid; c < B_ * 160; c += 320) {
        int b = c / 160, c4 = c % 160;
        *(ushort4*)&hbuf[b * 648 + c4 * 4] = *(const ushort4*)&src[b * H_ + c4 * 4];
      }
    }
    __syncthreads();

    f32x4 acc = {0.f, 0.f, 0.f, 0.f};
#pragma unroll
    for (int kk = 0; kk < 20; ++kk) {
      short8 a  = *(const short8*)&hbuf[l15 * 648 + kk * 32 + lq * 8];
      short8 bb = *(const short8*)&whh[(wid * 16 + l15) * 648 + kk * 32 + lq * 8];
      acc = MFMA(a, bb, acc);
    }
#pragma unroll
    for (int r = 0; r < 4; ++r)
      pre[(lq * 4 + r) * 80 + wid * 16 + l15] = acc[r];
    __syncthreads();

    {
      const int b = tid / 20, u = tid % 20;
      size_t xbase = ((size_t)((dir * B_ + b) * S_ + t)) * G4_ + J0 + u;
      float xi, xf, xg, xo;
      if (XPF32) {
        const float* xr = (const float*)xp_ + xbase;
        xi = xr[0]; xf = xr[640]; xg = xr[1280]; xo = xr[1920];
      } else {
        const unsigned short* xr = (const unsigned short*)xp_ + xbase;
        xi = bf2f(xr[0]); xf = bf2f(xr[640]); xg = bf2f(xr[1280]); xo = bf2f(xr[1920]);
      }
      float gi = pre[b * 80 + u]        + xi;
      float gf = pre[b * 80 + 20 + u]   + xf;
      float gg = pre[b * 80 + 40 + u]   + xg;
      float go = pre[b * 80 + 60 + u]   + xo;
      float i_ = sigm(gi), f_ = sigm(gf);
      float g_ = tanh_c(gg), o_ = sigm(go);
      float c2 = f_ * cst[tid] + i_ * g_;
      float h2 = o_ * tanh_c(c2);
      bool valid = t < len_s[b];
      float cn = valid ? c2 : cst[tid];
      float hn = valid ? h2 : hst[tid];
      cst[tid] = cn; hst[tid] = hn;
      h_ex[((size_t)(dir * 2 + ((s + 1) & 1)) * B_ + b) * H_ + J0 + u] = f2bf(hn);
      float yv = valid ? hn : 0.f;
      out_bf[((size_t)(b * S_ + t)) * DA_ + dir * H_ + J0 + u] = f2bf(yv);
    }

    // ---- step barrier across the 32 WGs of this direction
    __syncthreads();
    const int target = flag_base + s + 1;
    if (tid == 0) {
      __threadfence();   // publish this WG's h_ex writes device-wide (cross-XCD)
      __hip_atomic_store(&flags[wg * 32], target,
                         __ATOMIC_RELEASE, __HIP_MEMORY_SCOPE_AGENT);
    }
    if (wid == 0) {
      const int fidx = (dir * 32 + (lane & 31)) * 32;
      for (;;) {
        int v = __hip_atomic_load(&flags[fidx],
                                  __ATOMIC_RELAXED, __HIP_MEMORY_SCOPE_AGENT);
        if (__all(v >= target)) break;
        __builtin_amdgcn_s_sleep(1);
      }
    }
    __syncthreads();
    __threadfence();     // acquire: discard stale cached h_ex before next step's reads
  }
}

// ---------------------------------------------------------------- fused attention + residual
// grid = B*NH*8, 256 threads. Per wave: 16 q rows, full 512-col scores in regs,
// wave-local softmax, P in swizzled LDS, PV from transposed V, out = h1 + ctx.
__global__ __launch_bounds__(256)
void attn_fused(const unsigned short* __restrict__ q, const unsigned short* __restrict__ k,
                const unsigned short* __restrict__ vT, const float* __restrict__ mask,
                const unsigned short* __restrict__ h1, float* __restrict__ out)
{
  __shared__ unsigned short p_lds[64 * 512];
  const int tid = threadIdx.x, lane = tid & 63, wid = tid >> 6;
  const int bx = blockIdx.x;
  const int b = bx / 80, rem = bx % 80, h = rem / 8, qt = rem % 8;
  const int l15 = lane & 15, lq = lane >> 4;
  const int qrow0 = qt * 64 + wid * 16;

  short8 qf[4];
  {
    const unsigned short* qb = q + ((size_t)(b * S_ + qrow0 + l15)) * DA_ + h * HD_ + lq * 8;
#pragma unroll
    for (int ks = 0; ks < 4; ++ks) qf[ks] = *(const short8*)(qb + ks * 32);
  }
  f32x4 sc[32];
#pragma unroll
  for (int nt = 0; nt < 32; ++nt) {
    f32x4 a = {0.f, 0.f, 0.f, 0.f};
    const unsigned short* kb = k + ((size_t)(b * S_ + nt * 16 + l15)) * DA_ + h * HD_ + lq * 8;
#pragma unroll
    for (int ks = 0; ks < 4; ++ks) {
      short8 bf = *(const short8*)(kb + ks * 32);
      a = MFMA(qf[ks], bf, a);
    }
    sc[nt] = a;
  }
  const float scl = 0.08838834764831845f;  // 1/sqrt(128)
  float mx[4] = {-1e30f, -1e30f, -1e30f, -1e30f};
#pragma unroll
  for (int nt = 0; nt < 32; ++nt) {
    float mv = mask[b * S_ + nt * 16 + l15];
#pragma unroll
    for (int r = 0; r < 4; ++r) {
      float v = sc[nt][r] * scl + mv;
      sc[nt][r] = v;
      mx[r] = fmaxf(mx[r], v);
    }
  }
#pragma unroll
  for (int r = 0; r < 4; ++r) {
    mx[r] = fmaxf(mx[r], __shfl_xor(mx[r], 1));
    mx[r] = fmaxf(mx[r], __shfl_xor(mx[r], 2));
    mx[r] = fmaxf(mx[r], __shfl_xor(mx[r], 4));
    mx[r] = fmaxf(mx[r], __shfl_xor(mx[r], 8));
  }
  float sm[4] = {0.f, 0.f, 0.f, 0.f};
#pragma unroll
  for (int nt = 0; nt < 32; ++nt)
#pragma unroll
    for (int r = 0; r < 4; ++r) {
      float p = __expf(sc[nt][r] - mx[r]);
      sc[nt][r] = p; sm[r] += p;
    }
#pragma unroll
  for (int r = 0; r < 4; ++r) {
    sm[r] += __shfl_xor(sm[r], 1);
    sm[r] += __shfl_xor(sm[r], 2);
    sm[r] += __shfl_xor(sm[r], 4);
    sm[r] += __shfl_xor(sm[r], 8);
    sm[r] = 1.0f / sm[r];
  }
#pragma unroll
  for (int nt = 0; nt < 32; ++nt)
#pragma unroll
    for (int r = 0; r < 4; ++r) {
      int row = wid * 16 + lq * 4 + r;
      int byte = row * 1024 + (nt * 16 + l15) * 2;
      byte ^= (row & 7) << 4;
      *(unsigned short*)((char*)p_lds + byte) = f2bf(sc[nt][r] * sm[r]);
    }
  __syncthreads();

  f32x4 oa[8] = {};
#pragma unroll
  for (int kk = 0; kk < 16; ++kk) {
    int row = wid * 16 + l15;
    int byte = row * 1024 + (kk * 32 + lq * 8) * 2;
    byte ^= (row & 7) << 4;
    short8 pa = *(const short8*)((char*)p_lds + byte);
    const unsigned short* vb = vT + ((size_t)(b * NH_ + h) * HD_ + l15) * S_ + kk * 32 + lq * 8;
#pragma unroll
    for (int n = 0; n < 8; ++n) {
      short8 bv = *(const short8*)(vb + n * 16 * S_);
      oa[n] = MFMA(pa, bv, oa[n]);
    }
  }
#pragma unroll
  for (int n = 0; n < 8; ++n)
#pragma unroll
    for (int r = 0; r < 4; ++r) {
      int row = qrow0 + lq * 4 + r;
      int col = h * HD_ + n * 16 + l15;
      size_t idx = ((size_t)(b * S_ + row)) * DA_ + col;
      out[idx] = bf2f(h1[idx]) + oa[n][r];
    }
}

// ---------------------------------------------------------------- host
extern "C" void kernel_launch(void* const* d_in, const int* in_sizes, int n_in,
                              void* d_out, int out_size, void* d_ws, size_t ws_size,
                              hipStream_t stream) {
  const float* x    = (const float*)d_in[0];
  const float* mask = (const float*)d_in[1];
  const int*   lens = (const int*)d_in[2];
  const float* Wih0 = (const float*)d_in[3];
  const float* Whh0 = (const float*)d_in[4];
  const float* b0   = (const float*)d_in[5];
  const float* Wih1 = (const float*)d_in[6];
  const float* Whh1 = (const float*)d_in[7];
  const float* b1   = (const float*)d_in[8];
  const float* Wq   = (const float*)d_in[9];
  const float* bq   = (const float*)d_in[10];
  const float* Wk   = (const float*)d_in[11];
  const float* bk   = (const float*)d_in[12];
  const float* Wv   = (const float*)d_in[13];
  const float* bv   = (const float*)d_in[14];

  // ---- sizes (all multiples of 256 B)
  const size_t SZ_wb_ih1 = (size_t)2 * G4_ * DA_ * 2;       // 13,107,200
  const size_t SZ_wb_hh  = (size_t)2 * G4_ * H_ * 2;        //  6,553,600
  const size_t SZ_wb_qkv = (size_t)DA_ * DA_ * 2;           //  3,276,800
  const size_t SZ_tok_bf = (size_t)B_ * S_ * DA_ * 2;       // 20,971,520
  const size_t SZ_h_ex   = (size_t)2 * 2 * B_ * H_ * 2;     //    163,840
  const size_t SZ_flags  = (size_t)64 * 32 * 4;             //      8,192
  const size_t SZ_xbf    = (size_t)B_ * S_ * DM_ * 2;       // 12,582,912
  const size_t SZ_wb_ih0 = (size_t)2 * G4_ * DM_ * 2;       //  7,864,320
  const size_t SZ_regA   = SZ_xbf + SZ_wb_ih0 + SZ_wb_hh;   // 27,000,832 (>= qbf)
  const size_t SZ_xp_f32 = (size_t)2 * B_ * S_ * G4_ * 4;   // 167,772,160
  const size_t SZ_xp_bf  = SZ_xp_f32 / 2;                   //  83,886,080

  const size_t persist = SZ_wb_ih1 + SZ_wb_hh + 3 * SZ_wb_qkv + 2 * SZ_tok_bf
                       + SZ_h_ex + SZ_flags;                // 71,606,272
  const size_t need_A = persist + SZ_regA + SZ_xp_f32;      // 266,379,264
  const bool xpf32 = (ws_size >= need_A + 4096);

  char* ws = (char*)d_ws;
  size_t off = 0;
  auto alloc = [&](size_t bytes) { char* p = ws + off; off += bytes; return p; };

  unsigned short* wb_ih1 = (unsigned short*)alloc(SZ_wb_ih1);
  unsigned short* wb_hh1 = (unsigned short*)alloc(SZ_wb_hh);
  unsigned short* wb_q   = (unsigned short*)alloc(SZ_wb_qkv);
  unsigned short* wb_k   = (unsigned short*)alloc(SZ_wb_qkv);
  unsigned short* wb_v   = (unsigned short*)alloc(SZ_wb_qkv);
  unsigned short* h0bf   = (unsigned short*)alloc(SZ_tok_bf);
  unsigned short* h1bf   = (unsigned short*)alloc(SZ_tok_bf);
  unsigned short* h_ex   = (unsigned short*)alloc(SZ_h_ex);
  int*            flags  = (int*)alloc(SZ_flags);

  char* regA = alloc(SZ_regA);          // xbf | wb_ih0 | wb_hh0 ; later qbf
  unsigned short* xbf    = (unsigned short*)regA;
  unsigned short* wb_ih0 = (unsigned short*)(regA + SZ_xbf);
  unsigned short* wb_hh0 = (unsigned short*)(regA + SZ_xbf + SZ_wb_ih0);
  unsigned short* qbf    = (unsigned short*)regA;

  char* regB = alloc(xpf32 ? SZ_xp_f32 : SZ_xp_bf);  // xp ; later kbf|vtbf
  void*           xp     = (void*)regB;
  unsigned short* kbf    = (unsigned short*)regB;
  unsigned short* vtbf   = (unsigned short*)(regB + SZ_tok_bf);

  // zero h_ex + flags (adjacent)
  hipMemsetAsync(h_ex, 0, SZ_h_ex + SZ_flags, stream);

  auto cast = [&](const float* s, unsigned short* d, size_t n) {
    int n4 = (int)(n / 4);
    cast_f32_bf16<<<(n4 + 255) / 256, 256, 0, stream>>>(s, d, n4);
  };
  cast(Wih0, wb_ih0, (size_t)2 * G4_ * DM_);
  cast(Whh0, wb_hh0, (size_t)2 * G4_ * H_);
  cast(Wih1, wb_ih1, (size_t)2 * G4_ * DA_);
  cast(Whh1, wb_hh1, (size_t)2 * G4_ * H_);
  cast(Wq, wb_q, (size_t)DA_ * DA_);
  cast(Wk, wb_k, (size_t)DA_ * DA_);
  cast(Wv, wb_v, (size_t)DA_ * DA_);
  cast(x, xbf, (size_t)B_ * S_ * DM_);

  const int M = B_ * S_;  // 8192
  const size_t xp_dir_stride = (size_t)M * G4_;  // elements

  // layer-0 input projection (f32 or bf16 xp)
  if (xpf32) {
    gemm_abt<0><<<(M / 128) * (G4_ / 128), 256, 0, stream>>>(
        xbf, wb_ih0, b0, xp, M, G4_, DM_);
    gemm_abt<0><<<(M / 128) * (G4_ / 128), 256, 0, stream>>>(
        xbf, wb_ih0 + (size_t)G4_ * DM_, b0 + G4_,
        (float*)xp + xp_dir_stride, M, G4_, DM_);
  } else {
    gemm_abt<1><<<(M / 128) * (G4_ / 128), 256, 0, stream>>>(
        xbf, wb_ih0, b0, xp, M, G4_, DM_);
    gemm_abt<1><<<(M / 128) * (G4_ / 128), 256, 0, stream>>>(
        xbf, wb_ih0 + (size_t)G4_ * DM_, b0 + G4_,
        (unsigned short*)xp + xp_dir_stride, M, G4_, DM_);
  }
  // layer-0 recurrence
  if (xpf32)
    bilstm_layer<true><<<64, 320, 0, stream>>>(xp, wb_hh0, lens, h_ex, flags, 0, h0bf);
  else
    bilstm_layer<false><<<64, 320, 0, stream>>>(xp, wb_hh0, lens, h_ex, flags, 0, h0bf);

  // layer-1 input projection (reuse xp)
  if (xpf32) {
    gemm_abt<0><<<(M / 128) * (G4_ / 128), 256, 0, stream>>>(
        h0bf, wb_ih1, b1, xp, M, G4_, DA_);
    gemm_abt<0><<<(M / 128) * (G4_ / 128), 256, 0, stream>>>(
        h0bf, wb_ih1 + (size_t)G4_ * DA_, b1 + G4_,
        (float*)xp + xp_dir_stride, M, G4_, DA_);
  } else {
    gemm_abt<1><<<(M / 128) * (G4_ / 128), 256, 0, stream>>>(
        h0bf, wb_ih1, b1, xp, M, G4_, DA_);
    gemm_abt<1><<<(M / 128) * (G4_ / 128), 256, 0, stream>>>(
        h0bf, wb_ih1 + (size_t)G4_ * DA_, b1 + G4_,
        (unsigned short*)xp + xp_dir_stride, M, G4_, DA_);
  }
  // reset h state; layer-1 recurrence (flags keep counting from 512)
  hipMemsetAsync(h_ex, 0, SZ_h_ex, stream);
  if (xpf32)
    bilstm_layer<true><<<64, 320, 0, stream>>>(xp, wb_hh1, lens, h_ex, flags, S_, h1bf);
  else
    bilstm_layer<false><<<64, 320, 0, stream>>>(xp, wb_hh1, lens, h_ex, flags, S_, h1bf);

  // QKV (qbf overlays dead xbf/wb_ih0; kbf/vtbf overlay dead xp)
  gemm_abt<1><<<(M / 128) * (DA_ / 128), 256, 0, stream>>>(
      h1bf, wb_q, bq, qbf, M, DA_, DA_);
  gemm_abt<1><<<(M / 128) * (DA_ / 128), 256, 0, stream>>>(
      h1bf, wb_k, bk, kbf, M, DA_, DA_);
  gemm_abt<2><<<(M / 128) * (DA_ / 128), 256, 0, stream>>>(
      h1bf, wb_v, bv, vtbf, M, DA_, DA_);
  // attention + residual -> d_out
  attn_fused<<<B_ * NH_ * 8, 256, 0, stream>>>(qbf, kbf, vtbf, mask, h1bf,
                                               (float*)d_out);
}

// Round 3
// 4131.841 us; speedup vs baseline: 2.9080x; 2.9080x over previous
//
#include <hip/hip_runtime.h>

typedef __attribute__((ext_vector_type(8))) short short8;
typedef __attribute__((ext_vector_type(4))) float f32x4;
typedef __attribute__((ext_vector_type(4))) unsigned int u32x4;

#define MFMA(a,b,c) __builtin_amdgcn_mfma_f32_16x16x32_bf16((a),(b),(c),0,0,0)

#define B_  16
#define S_  512
#define DM_ 768
#define H_  640
#define G4_ 2560
#define DA_ 1280
#define NH_ 10
#define HD_ 128

static __device__ __forceinline__ unsigned short f2bf(float v) {
  unsigned u = __builtin_bit_cast(unsigned, v);
  u = (u + 0x7fffu + ((u >> 16) & 1u)) >> 16;
  return (unsigned short)u;
}
static __device__ __forceinline__ float bf2f(unsigned short u) {
  return __builtin_bit_cast(float, (unsigned)u << 16);
}
static __device__ __forceinline__ float sigm(float x) { return 1.0f / (1.0f + __expf(-x)); }
static __device__ __forceinline__ float tanh_c(float x) {
  x = fminf(fmaxf(x, -15.0f), 15.0f);
  float e = __expf(2.0f * x);
  return (e - 1.0f) / (e + 1.0f);
}

// ---- coherent (LLC-level, L1/L2-bypassing) access helpers -------------------
static __device__ __forceinline__ u32x4 load_coh16(const void* p) {
  u32x4 r;
  asm volatile("global_load_dwordx4 %0, %1, off sc0 sc1"
               : "=v"(r) : "v"(p) : "memory");
  return r;
}
static __device__ __forceinline__ void store_coh_u16(void* p, unsigned v) {
  asm volatile("global_store_short %0, %1, off sc0 sc1"
               :: "v"(p), "v"(v) : "memory");
}
static __device__ __forceinline__ void store_coh_u32(void* p, unsigned v) {
  asm volatile("global_store_dword %0, %1, off sc0 sc1"
               :: "v"(p), "v"(v) : "memory");
}
static __device__ __forceinline__ unsigned load_coh_u32(const void* p) {
  unsigned r;
  asm volatile("global_load_dword %0, %1, off sc0 sc1"
               : "=v"(r) : "v"(p) : "memory");
  return r;
}
#define WAIT_VM0() asm volatile("s_waitcnt vmcnt(0)" ::: "memory")

// ---------------------------------------------------------------- cast f32->bf16
__global__ __launch_bounds__(256)
void cast_f32_bf16(const float* __restrict__ src, unsigned short* __restrict__ dst, int n4) {
  int i = blockIdx.x * 256 + threadIdx.x;
  if (i >= n4) return;
  float4 v = reinterpret_cast<const float4*>(src)[i];
  ushort4 o;
  o.x = f2bf(v.x); o.y = f2bf(v.y); o.z = f2bf(v.z); o.w = f2bf(v.w);
  reinterpret_cast<ushort4*>(dst)[i] = o;
}

// ---------------------------------------------------------------- GEMM  C = A @ W^T + bias
// OUT_MODE 1: bf16 C[M][N]; 2: bf16 per-head-transposed V; 3: f32 xp-scatter
// [slice][t][b][gate*20+u]; 4: bf16 xp-scatter.
__device__ __forceinline__ void gload_lds16(void* lds, const void* g) {
  __builtin_amdgcn_global_load_lds(
      (const __attribute__((address_space(1))) unsigned int*)g,
      (__attribute__((address_space(3))) unsigned int*)lds, 16, 0, 0);
}

template<int OUT_MODE>
__global__ __launch_bounds__(256)
void gemm_abt(const unsigned short* __restrict__ A, const unsigned short* __restrict__ W,
              const float* __restrict__ bias, void* __restrict__ Cout,
              int M, int N, int K) {
  __shared__ unsigned short lA[128 * 32];
  __shared__ unsigned short lB[128 * 32];
  const int tid = threadIdx.x;
  const int lane = tid & 63, wid = tid >> 6;
  const int nbn = N >> 7;
  const int mi = blockIdx.x / nbn, ni = blockIdx.x % nbn;
  const int l15 = lane & 15, lq = lane >> 4;

  f32x4 acc[4][4] = {};

  for (int k0 = 0; k0 < K; k0 += 32) {
#pragma unroll
    for (int part = 0; part < 2; ++part) {
      int linear = part * 256 + tid;
      int r = linear >> 2, cc = linear & 3;
      const unsigned short* ga = A + (size_t)(mi * 128 + r) * K + k0 + cc * 8;
      const unsigned short* gb = W + (size_t)(ni * 128 + r) * K + k0 + cc * 8;
      gload_lds16(&lA[(part * 256 + wid * 64) * 8], ga);
      gload_lds16(&lB[(part * 256 + wid * 64) * 8], gb);
    }
    __syncthreads();
    const int wm = (wid >> 1) * 64, wn = (wid & 1) * 64;
    short8 af[4], bfr[4];
#pragma unroll
    for (int m = 0; m < 4; ++m)
      af[m] = *(const short8*)&lA[(wm + m * 16 + l15) * 32 + lq * 8];
#pragma unroll
    for (int n = 0; n < 4; ++n)
      bfr[n] = *(const short8*)&lB[(wn + n * 16 + l15) * 32 + lq * 8];
#pragma unroll
    for (int m = 0; m < 4; ++m)
#pragma unroll
      for (int n = 0; n < 4; ++n)
        acc[m][n] = MFMA(af[m], bfr[n], acc[m][n]);
    __syncthreads();
  }

  const int wm = (wid >> 1) * 64, wn = (wid & 1) * 64;
#pragma unroll
  for (int n = 0; n < 4; ++n) {
    int col = ni * 128 + wn + n * 16 + l15;
    float bv = bias[col];
#pragma unroll
    for (int m = 0; m < 4; ++m) {
#pragma unroll
      for (int r = 0; r < 4; ++r) {
        int row = mi * 128 + wm + m * 16 + lq * 4 + r;
        float v = acc[m][n][r] + bv;
        if (OUT_MODE == 1) {
          ((unsigned short*)Cout)[(size_t)row * N + col] = f2bf(v);
        } else if (OUT_MODE == 2) {
          int bb = row >> 9, s = row & 511, hh = col >> 7, d = col & 127;
          ((unsigned short*)Cout)[(((size_t)(bb * NH_ + hh) * HD_ + d) << 9) + s] = f2bf(v);
        } else {
          int gate = col / 640, unit = col % 640;
          int slice = unit / 20, uu = unit % 20;
          int bb = row >> 9, tt = row & 511;
          size_t idx = (((size_t)slice * S_ + tt) * B_ + bb) * 80 + gate * 20 + uu;
          if (OUT_MODE == 3) ((float*)Cout)[idx] = v;
          else               ((unsigned short*)Cout)[idx] = f2bf(v);
        }
      }
    }
  }
}

// ---------------------------------------------------------------- persistent BiLSTM layer
// grid = 64 WGs (32/dir), 320 threads. Each WG owns 20 hidden units (80 Whh rows in LDS).
// h exchanged via LLC-coherent (sc0 sc1) loads/stores; NO cache-maintenance fences.
// xp layout: [dir][slice(32)][S][B][80] (f32 or bf16), prefetched 1 step ahead.
template<bool XPF32>
__global__ __launch_bounds__(320)
void bilstm_layer(const void* __restrict__ xp_,
                  const unsigned short* __restrict__ whh_g, // [2][2560][640] bf16
                  const int* __restrict__ lengths,
                  unsigned short* __restrict__ h_ex,        // [2][2][16][640] bf16
                  int* __restrict__ flags, int flag_base,
                  unsigned short* __restrict__ out_bf)      // [B*S][1280] bf16
{
  __shared__ unsigned short whh[80 * 648];
  __shared__ unsigned short hbuf[16 * 648];
  __shared__ float pre[16 * 80];
  __shared__ float xpbuf[16 * 80];   // bf16 plan reuses low half
  __shared__ int len_s[16];

  const int tid = threadIdx.x;
  const int lane = tid & 63, wid = tid >> 6;
  const int wg = blockIdx.x;
  const int dir = wg >> 5, slice = wg & 31;
  const int J0 = slice * 20;
  const int l15 = lane & 15, lq = lane >> 4;

  // stage Whh slab (4 gates x 20 units = 80 rows)
  for (int c = tid; c < 80 * 160; c += 320) {
    int r = c / 160, c4 = c % 160;
    int grow = (r / 20) * H_ + J0 + (r % 20);
    *(ushort4*)&whh[r * 648 + c4 * 4] =
        *(const ushort4*)&whh_g[((size_t)dir * G4_ + grow) * H_ + c4 * 4];
  }
  if (tid < 16) len_s[tid] = lengths[tid];
  __syncthreads();

  // per-thread LSTM state (b = tid/20, u = tid%20)
  const int gb = tid / 20, gu = tid % 20;
  float c_st = 0.f, h_st = 0.f;

  // xp stream base for this (dir, slice)
  const char* xps;
  if (XPF32)
    xps = (const char*)xp_ + ((size_t)dir * 32 + slice) * S_ * B_ * 80 * 4;
  else
    xps = (const char*)xp_ + ((size_t)dir * 32 + slice) * S_ * B_ * 80 * 2;

  // prefetch step 0 xp block
  float4  xv_f;
  ushort4 xv_h;
  {
    int t0 = dir ? (S_ - 1) : 0;
    if (XPF32) xv_f = *(const float4*)(xps + ((size_t)t0 * 1280 + tid * 4) * 4);
    else       xv_h = *(const ushort4*)(xps + ((size_t)t0 * 1280 + tid * 4) * 2);
  }

  for (int s = 0; s < S_; ++s) {
    const int t = dir ? (S_ - 1 - s) : s;
    // prefetch next step's xp block (regular cached loads)
    float4  xn_f;
    ushort4 xn_h;
    {
      int tn = dir ? (S_ - 2 - s) : (s + 1);
      tn = tn < 0 ? 0 : (tn > S_ - 1 ? S_ - 1 : tn);
      if (XPF32) xn_f = *(const float4*)(xps + ((size_t)tn * 1280 + tid * 4) * 4);
      else       xn_h = *(const ushort4*)(xps + ((size_t)tn * 1280 + tid * 4) * 2);
    }

    // coherent read of full h vector [16][640] bf16 -> hbuf
    {
      const unsigned short* src = h_ex + (size_t)(dir * 2 + (s & 1)) * B_ * H_;
      u32x4 hv[4];
      int bs[4], os[4];
#pragma unroll
      for (int j = 0; j < 4; ++j) {
        int c = tid + j * 320;          // 1280 chunks of 16B
        bs[j] = c / 80; os[j] = c % 80; // chunk offset within b-row
        hv[j] = load_coh16(src + (size_t)bs[j] * 640 + os[j] * 8);
      }
      WAIT_VM0();
      __builtin_amdgcn_sched_barrier(0);
#pragma unroll
      for (int j = 0; j < 4; ++j)
        *(u32x4*)&hbuf[bs[j] * 648 + os[j] * 8] = hv[j];
    }
    // publish current xp block to LDS
    if (XPF32) {
      *(float4*)&xpbuf[tid * 4] = xv_f;
    } else {
      *(ushort4*)&((unsigned short*)xpbuf)[tid * 4] = xv_h;
    }
    __syncthreads();   // A: hbuf + xpbuf ready

    // h @ Whh_slab^T : 16x80 output, two independent MFMA chains
    f32x4 acc0 = {0.f, 0.f, 0.f, 0.f}, acc1 = {0.f, 0.f, 0.f, 0.f};
#pragma unroll
    for (int kk = 0; kk < 20; kk += 2) {
      short8 a0 = *(const short8*)&hbuf[l15 * 648 + kk * 32 + lq * 8];
      short8 b0v = *(const short8*)&whh[(wid * 16 + l15) * 648 + kk * 32 + lq * 8];
      acc0 = MFMA(a0, b0v, acc0);
      short8 a1 = *(const short8*)&hbuf[l15 * 648 + (kk + 1) * 32 + lq * 8];
      short8 b1v = *(const short8*)&whh[(wid * 16 + l15) * 648 + (kk + 1) * 32 + lq * 8];
      acc1 = MFMA(a1, b1v, acc1);
    }
#pragma unroll
    for (int r = 0; r < 4; ++r)
      pre[(lq * 4 + r) * 80 + wid * 16 + l15] = acc0[r] + acc1[r];
    __syncthreads();   // B: pre ready

    // gate compute (thread owns (gb,gu))
    {
      float xi, xf, xg, xo;
      if (XPF32) {
        xi = xpbuf[gb * 80 + gu];
        xf = xpbuf[gb * 80 + 20 + gu];
        xg = xpbuf[gb * 80 + 40 + gu];
        xo = xpbuf[gb * 80 + 60 + gu];
      } else {
        const unsigned short* xb = (const unsigned short*)xpbuf;
        xi = bf2f(xb[gb * 80 + gu]);
        xf = bf2f(xb[gb * 80 + 20 + gu]);
        xg = bf2f(xb[gb * 80 + 40 + gu]);
        xo = bf2f(xb[gb * 80 + 60 + gu]);
      }
      float gi = pre[gb * 80 + gu]      + xi;
      float gf = pre[gb * 80 + 20 + gu] + xf;
      float gg = pre[gb * 80 + 40 + gu] + xg;
      float go = pre[gb * 80 + 60 + gu] + xo;
      float i_ = sigm(gi), f_ = sigm(gf);
      float g_ = tanh_c(gg), o_ = sigm(go);
      float c2 = f_ * c_st + i_ * g_;
      float h2 = o_ * tanh_c(c2);
      bool valid = t < len_s[gb];
      c_st = valid ? c2 : c_st;
      h_st = valid ? h2 : h_st;
      unsigned hb = f2bf(h_st);
      store_coh_u16(h_ex + (size_t)(dir * 2 + ((s + 1) & 1)) * B_ * H_
                         + (size_t)gb * H_ + J0 + gu, hb);
      float yv = valid ? h_st : 0.f;
      out_bf[((size_t)(gb * S_ + t)) * DA_ + dir * H_ + J0 + gu] = f2bf(yv);
    }

    // release: drain own stores, then flag
    WAIT_VM0();
    __syncthreads();   // C: all h stores drained
    const int target = flag_base + s + 1;
    if (tid == 0)
      store_coh_u32(flags + (size_t)wg * 32, (unsigned)target);
    if (wid == 0) {
      const int* fp = flags + (size_t)(dir * 32 + (lane & 31)) * 32;
      for (;;) {
        unsigned v = load_coh_u32(fp);
        WAIT_VM0();
        if (__all((int)v >= target)) break;
      }
    }
    __syncthreads();   // D: step complete
    xv_f = xn_f; xv_h = xn_h;
  }
}

// ---------------------------------------------------------------- fused attention + residual
__global__ __launch_bounds__(256)
void attn_fused(const unsigned short* __restrict__ q, const unsigned short* __restrict__ k,
                const unsigned short* __restrict__ vT, const float* __restrict__ mask,
                const unsigned short* __restrict__ h1, float* __restrict__ out)
{
  __shared__ unsigned short p_lds[64 * 512];
  const int tid = threadIdx.x, lane = tid & 63, wid = tid >> 6;
  const int bx = blockIdx.x;
  const int b = bx / 80, rem = bx % 80, h = rem / 8, qt = rem % 8;
  const int l15 = lane & 15, lq = lane >> 4;
  const int qrow0 = qt * 64 + wid * 16;

  short8 qf[4];
  {
    const unsigned short* qb = q + ((size_t)(b * S_ + qrow0 + l15)) * DA_ + h * HD_ + lq * 8;
#pragma unroll
    for (int ks = 0; ks < 4; ++ks) qf[ks] = *(const short8*)(qb + ks * 32);
  }
  f32x4 sc[32];
#pragma unroll
  for (int nt = 0; nt < 32; ++nt) {
    f32x4 a = {0.f, 0.f, 0.f, 0.f};
    const unsigned short* kb = k + ((size_t)(b * S_ + nt * 16 + l15)) * DA_ + h * HD_ + lq * 8;
#pragma unroll
    for (int ks = 0; ks < 4; ++ks) {
      short8 bf = *(const short8*)(kb + ks * 32);
      a = MFMA(qf[ks], bf, a);
    }
    sc[nt] = a;
  }
  const float scl = 0.08838834764831845f;  // 1/sqrt(128)
  float mx[4] = {-1e30f, -1e30f, -1e30f, -1e30f};
#pragma unroll
  for (int nt = 0; nt < 32; ++nt) {
    float mv = mask[b * S_ + nt * 16 + l15];
#pragma unroll
    for (int r = 0; r < 4; ++r) {
      float v = sc[nt][r] * scl + mv;
      sc[nt][r] = v;
      mx[r] = fmaxf(mx[r], v);
    }
  }
#pragma unroll
  for (int r = 0; r < 4; ++r) {
    mx[r] = fmaxf(mx[r], __shfl_xor(mx[r], 1));
    mx[r] = fmaxf(mx[r], __shfl_xor(mx[r], 2));
    mx[r] = fmaxf(mx[r], __shfl_xor(mx[r], 4));
    mx[r] = fmaxf(mx[r], __shfl_xor(mx[r], 8));
  }
  float sm[4] = {0.f, 0.f, 0.f, 0.f};
#pragma unroll
  for (int nt = 0; nt < 32; ++nt)
#pragma unroll
    for (int r = 0; r < 4; ++r) {
      float p = __expf(sc[nt][r] - mx[r]);
      sc[nt][r] = p; sm[r] += p;
    }
#pragma unroll
  for (int r = 0; r < 4; ++r) {
    sm[r] += __shfl_xor(sm[r], 1);
    sm[r] += __shfl_xor(sm[r], 2);
    sm[r] += __shfl_xor(sm[r], 4);
    sm[r] += __shfl_xor(sm[r], 8);
    sm[r] = 1.0f / sm[r];
  }
#pragma unroll
  for (int nt = 0; nt < 32; ++nt)
#pragma unroll
    for (int r = 0; r < 4; ++r) {
      int row = wid * 16 + lq * 4 + r;
      int byte = row * 1024 + (nt * 16 + l15) * 2;
      byte ^= (row & 7) << 4;
      *(unsigned short*)((char*)p_lds + byte) = f2bf(sc[nt][r] * sm[r]);
    }
  __syncthreads();

  f32x4 oa[8] = {};
#pragma unroll
  for (int kk = 0; kk < 16; ++kk) {
    int row = wid * 16 + l15;
    int byte = row * 1024 + (kk * 32 + lq * 8) * 2;
    byte ^= (row & 7) << 4;
    short8 pa = *(const short8*)((char*)p_lds + byte);
    const unsigned short* vb = vT + ((size_t)(b * NH_ + h) * HD_ + l15) * S_ + kk * 32 + lq * 8;
#pragma unroll
    for (int n = 0; n < 8; ++n) {
      short8 bv = *(const short8*)(vb + n * 16 * S_);
      oa[n] = MFMA(pa, bv, oa[n]);
    }
  }
#pragma unroll
  for (int n = 0; n < 8; ++n)
#pragma unroll
    for (int r = 0; r < 4; ++r) {
      int row = qrow0 + lq * 4 + r;
      int col = h * HD_ + n * 16 + l15;
      size_t idx = ((size_t)(b * S_ + row)) * DA_ + col;
      out[idx] = bf2f(h1[idx]) + oa[n][r];
    }
}

// ---------------------------------------------------------------- host
extern "C" void kernel_launch(void* const* d_in, const int* in_sizes, int n_in,
                              void* d_out, int out_size, void* d_ws, size_t ws_size,
                              hipStream_t stream) {
  const float* x    = (const float*)d_in[0];
  const float* mask = (const float*)d_in[1];
  const int*   lens = (const int*)d_in[2];
  const float* Wih0 = (const float*)d_in[3];
  const float* Whh0 = (const float*)d_in[4];
  const float* b0   = (const float*)d_in[5];
  const float* Wih1 = (const float*)d_in[6];
  const float* Whh1 = (const float*)d_in[7];
  const float* b1   = (const float*)d_in[8];
  const float* Wq   = (const float*)d_in[9];
  const float* bq   = (const float*)d_in[10];
  const float* Wk   = (const float*)d_in[11];
  const float* bk   = (const float*)d_in[12];
  const float* Wv   = (const float*)d_in[13];
  const float* bv   = (const float*)d_in[14];

  const size_t SZ_wb_ih1 = (size_t)2 * G4_ * DA_ * 2;
  const size_t SZ_wb_hh  = (size_t)2 * G4_ * H_ * 2;
  const size_t SZ_wb_qkv = (size_t)DA_ * DA_ * 2;
  const size_t SZ_tok_bf = (size_t)B_ * S_ * DA_ * 2;
  const size_t SZ_h_ex   = (size_t)2 * 2 * B_ * H_ * 2;
  const size_t SZ_flags  = (size_t)64 * 32 * 4;
  const size_t SZ_xbf    = (size_t)B_ * S_ * DM_ * 2;
  const size_t SZ_wb_ih0 = (size_t)2 * G4_ * DM_ * 2;
  const size_t SZ_regA   = SZ_xbf + SZ_wb_ih0 + SZ_wb_hh;
  const size_t SZ_xp_f32 = (size_t)2 * B_ * S_ * G4_ * 4;
  const size_t SZ_xp_bf  = SZ_xp_f32 / 2;

  const size_t persist = SZ_wb_ih1 + SZ_wb_hh + 3 * SZ_wb_qkv + 2 * SZ_tok_bf
                       + SZ_h_ex + SZ_flags;
  const size_t need_A = persist + SZ_regA + SZ_xp_f32;
  const bool xpf32 = (ws_size >= need_A + 4096);

  char* ws = (char*)d_ws;
  size_t off = 0;
  auto alloc = [&](size_t bytes) { char* p = ws + off; off += bytes; return p; };

  unsigned short* wb_ih1 = (unsigned short*)alloc(SZ_wb_ih1);
  unsigned short* wb_hh1 = (unsigned short*)alloc(SZ_wb_hh);
  unsigned short* wb_q   = (unsigned short*)alloc(SZ_wb_qkv);
  unsigned short* wb_k   = (unsigned short*)alloc(SZ_wb_qkv);
  unsigned short* wb_v   = (unsigned short*)alloc(SZ_wb_qkv);
  unsigned short* h0bf   = (unsigned short*)alloc(SZ_tok_bf);
  unsigned short* h1bf   = (unsigned short*)alloc(SZ_tok_bf);
  unsigned short* h_ex   = (unsigned short*)alloc(SZ_h_ex);
  int*            flags  = (int*)alloc(SZ_flags);

  char* regA = alloc(SZ_regA);
  unsigned short* xbf    = (unsigned short*)regA;
  unsigned short* wb_ih0 = (unsigned short*)(regA + SZ_xbf);
  unsigned short* wb_hh0 = (unsigned short*)(regA + SZ_xbf + SZ_wb_ih0);
  unsigned short* qbf    = (unsigned short*)regA;

  char* regB = alloc(xpf32 ? SZ_xp_f32 : SZ_xp_bf);
  void*           xp     = (void*)regB;
  unsigned short* kbf    = (unsigned short*)regB;
  unsigned short* vtbf   = (unsigned short*)(regB + SZ_tok_bf);

  hipMemsetAsync(h_ex, 0, SZ_h_ex + SZ_flags, stream);

  auto cast = [&](const float* s, unsigned short* d, size_t n) {
    int n4 = (int)(n / 4);
    cast_f32_bf16<<<(n4 + 255) / 256, 256, 0, stream>>>(s, d, n4);
  };
  cast(Wih0, wb_ih0, (size_t)2 * G4_ * DM_);
  cast(Whh0, wb_hh0, (size_t)2 * G4_ * H_);
  cast(Wih1, wb_ih1, (size_t)2 * G4_ * DA_);
  cast(Whh1, wb_hh1, (size_t)2 * G4_ * H_);
  cast(Wq, wb_q, (size_t)DA_ * DA_);
  cast(Wk, wb_k, (size_t)DA_ * DA_);
  cast(Wv, wb_v, (size_t)DA_ * DA_);
  cast(x, xbf, (size_t)B_ * S_ * DM_);

  const int M = B_ * S_;  // 8192
  const size_t xp_dir_elems = (size_t)32 * S_ * B_ * 80;  // per-dir element count

  // layer-0 input projection -> xp scatter layout
  if (xpf32) {
    gemm_abt<3><<<(M / 128) * (G4_ / 128), 256, 0, stream>>>(
        xbf, wb_ih0, b0, xp, M, G4_, DM_);
    gemm_abt<3><<<(M / 128) * (G4_ / 128), 256, 0, stream>>>(
        xbf, wb_ih0 + (size_t)G4_ * DM_, b0 + G4_,
        (float*)xp + xp_dir_elems, M, G4_, DM_);
    bilstm_layer<true><<<64, 320, 0, stream>>>(xp, wb_hh0, lens, h_ex, flags, 0, h0bf);
  } else {
    gemm_abt<4><<<(M / 128) * (G4_ / 128), 256, 0, stream>>>(
        xbf, wb_ih0, b0, xp, M, G4_, DM_);
    gemm_abt<4><<<(M / 128) * (G4_ / 128), 256, 0, stream>>>(
        xbf, wb_ih0 + (size_t)G4_ * DM_, b0 + G4_,
        (unsigned short*)xp + xp_dir_elems, M, G4_, DM_);
    bilstm_layer<false><<<64, 320, 0, stream>>>(xp, wb_hh0, lens, h_ex, flags, 0, h0bf);
  }

  // layer-1 input projection (reuse xp)
  if (xpf32) {
    gemm_abt<3><<<(M / 128) * (G4_ / 128), 256, 0, stream>>>(
        h0bf, wb_ih1, b1, xp, M, G4_, DA_);
    gemm_abt<3><<<(M / 128) * (G4_ / 128), 256, 0, stream>>>(
        h0bf, wb_ih1 + (size_t)G4_ * DA_, b1 + G4_,
        (float*)xp + xp_dir_elems, M, G4_, DA_);
  } else {
    gemm_abt<4><<<(M / 128) * (G4_ / 128), 256, 0, stream>>>(
        h0bf, wb_ih1, b1, xp, M, G4_, DA_);
    gemm_abt<4><<<(M / 128) * (G4_ / 128), 256, 0, stream>>>(
        h0bf, wb_ih1 + (size_t)G4_ * DA_, b1 + G4_,
        (unsigned short*)xp + xp_dir_elems, M, G4_, DA_);
  }
  hipMemsetAsync(h_ex, 0, SZ_h_ex, stream);
  if (xpf32)
    bilstm_layer<true><<<64, 320, 0, stream>>>(xp, wb_hh1, lens, h_ex, flags, S_, h1bf);
  else
    bilstm_layer<false><<<64, 320, 0, stream>>>(xp, wb_hh1, lens, h_ex, flags, S_, h1bf);

  // QKV
  gemm_abt<1><<<(M / 128) * (DA_ / 128), 256, 0, stream>>>(
      h1bf, wb_q, bq, qbf, M, DA_, DA_);
  gemm_abt<1><<<(M / 128) * (DA_ / 128), 256, 0, stream>>>(
      h1bf, wb_k, bk, kbf, M, DA_, DA_);
  gemm_abt<2><<<(M / 128) * (DA_ / 128), 256, 0, stream>>>(
      h1bf, wb_v, bv, vtbf, M, DA_, DA_);
  attn_fused<<<B_ * NH_ * 8, 256, 0, stream>>>(qbf, kbf, vtbf, mask, h1bf,
                                               (float*)d_out);
}